// Round 3
// baseline (111.319 us; speedup 1.0000x reference)
//
#include <hip/hip_runtime.h>
#include <math.h>

// ClipStyleContrastiveLoss on MI355X (gfx950).
// Math reduction (BETA=1 => imp==neg):
//   E = exp(L/t), exp(2L/t) = E^2
//   S1[i] = rowsum(E)[i] + colsum(E)[i] - 2*E[i,i]
//   S2[i] = rowsum(E^2)[i] + colsum(E^2)[i] - 2*E[i,i]^2
//   reweight = N*S2/S1 ; Ng = (reweight - tau*N*pos)/(1-tau), clamped at N*e^{-1/t}
//   loss = mean over B rows of log((pos+Ng+eps)/pos)
//
// R3: pass1 fully wave-autonomous — each wave owns 4 rows x 1024-col stripe.
// Zero LDS, zero barriers, zero atomics in pass1 (R1 bottleneck was 2M global
// atomics; R2 still had 32KB LDS capping occupancy at 5 blocks/CU + row atomics).

#define THREADS    256
// 1/(TEMPERATURE*ln2) = 2/ln2 : exp(x/t) = exp2(x*EXP_SCALE)
#define EXP_SCALE  2.885390081777927f

__global__ __launch_bounds__(THREADS) void pass1_kernel(
    const float* __restrict__ L,
    float* __restrict__ rowPE,    // [4][B]   per-col-stripe row sums of E
    float* __restrict__ rowPE2,   // [4][B]   per-col-stripe row sums of E^2
    float* __restrict__ colPE,    // [S][B]   per-row-stripe col partials of E   (S=B/4)
    float* __restrict__ colPE2,   // [S][B]
    int B)
{
    const int lane    = threadIdx.x & 63;
    const int wave    = threadIdx.x >> 6;
    const int x       = blockIdx.x;               // col stripe 0..3 (1024 cols each)
    const int stripe  = blockIdx.y * 4 + wave;    // row stripe id (4 rows each)
    const int row0    = stripe * 4;
    const int colBase = x * 1024 + lane * 4;      // lane's first col; chunks at +j*256

    float cE[16], cE2[16];
#pragma unroll
    for (int k = 0; k < 16; ++k) { cE[k] = 0.f; cE2[k] = 0.f; }

#pragma unroll
    for (int r = 0; r < 4; ++r) {
        const float* Lr = L + (size_t)(row0 + r) * B + colBase;
        float rs = 0.f, rs2 = 0.f;
#pragma unroll
        for (int j = 0; j < 4; ++j) {
            const float4 v = *reinterpret_cast<const float4*>(Lr + j * 256);
            float e0 = exp2f(v.x * EXP_SCALE);
            float e1 = exp2f(v.y * EXP_SCALE);
            float e2 = exp2f(v.z * EXP_SCALE);
            float e3 = exp2f(v.w * EXP_SCALE);
            float q0 = e0 * e0, q1 = e1 * e1, q2 = e2 * e2, q3 = e3 * e3;
            cE [j * 4 + 0] += e0; cE [j * 4 + 1] += e1;
            cE [j * 4 + 2] += e2; cE [j * 4 + 3] += e3;
            cE2[j * 4 + 0] += q0; cE2[j * 4 + 1] += q1;
            cE2[j * 4 + 2] += q2; cE2[j * 4 + 3] += q3;
            rs  += (e0 + e1) + (e2 + e3);
            rs2 += (q0 + q1) + (q2 + q3);
        }
        // full-wave reduce of this row's partial over the 1024-col stripe
#pragma unroll
        for (int off = 32; off > 0; off >>= 1) {
            rs  += __shfl_down(rs,  off, 64);
            rs2 += __shfl_down(rs2, off, 64);
        }
        if (lane == 0) {
            rowPE [(size_t)x * B + row0 + r] = rs;   // plain store — no atomic
            rowPE2[(size_t)x * B + row0 + r] = rs2;
        }
    }

    // store col partials, coalesced float4
    float* cpe  = colPE  + (size_t)stripe * B + colBase;
    float* cpe2 = colPE2 + (size_t)stripe * B + colBase;
#pragma unroll
    for (int j = 0; j < 4; ++j) {
        *reinterpret_cast<float4*>(cpe  + j * 256) =
            make_float4(cE [j*4+0], cE [j*4+1], cE [j*4+2], cE [j*4+3]);
        *reinterpret_cast<float4*>(cpe2 + j * 256) =
            make_float4(cE2[j*4+0], cE2[j*4+1], cE2[j*4+2], cE2[j*4+3]);
    }
}

// Merge: block handles 64 consecutive indices i; wave w sums a quarter of the
// S stripes (fully coalesced 256B/wave loads), LDS-combine, then per-col loss.
__global__ __launch_bounds__(THREADS) void pass2_kernel(
    const float* __restrict__ L,
    const float* __restrict__ rowPE,
    const float* __restrict__ rowPE2,
    const float* __restrict__ colPE,
    const float* __restrict__ colPE2,
    float* __restrict__ out,
    int B, int S)
{
    const int t    = threadIdx.x;
    const int lane = t & 63;
    const int wave = t >> 6;
    const int col  = blockIdx.x * 64 + lane;

    float se = 0.f, se2 = 0.f;
    const int k0 = wave * (S / 4), k1 = k0 + (S / 4);
#pragma unroll 8
    for (int k = k0; k < k1; ++k) {
        se  += colPE [(size_t)k * B + col];
        se2 += colPE2[(size_t)k * B + col];
    }
    __shared__ float2 part[4][64];
    part[wave][lane] = make_float2(se, se2);
    __syncthreads();

    if (wave == 0) {
        float colE  = (part[0][lane].x + part[1][lane].x) + (part[2][lane].x + part[3][lane].x);
        float colE2 = (part[0][lane].y + part[1][lane].y) + (part[2][lane].y + part[3][lane].y);
        const int i = col;
        float rowE  = (rowPE [i] + rowPE [B + i]) + (rowPE [2*B + i] + rowPE [3*B + i]);
        float rowE2 = (rowPE2[i] + rowPE2[B + i]) + (rowPE2[2*B + i] + rowPE2[3*B + i]);

        const float Nf = (float)(2 * B - 2);
        float dg = L[(size_t)i * B + i];
        float pe = exp2f(dg * EXP_SCALE);
        float S1 = rowE  + colE  - 2.f * pe;
        float S2 = rowE2 + colE2 - 2.f * (pe * pe);
        float rw = Nf * (S2 / S1);                        // N * sum(neg^2)/sum(neg)
        float Ng = (rw - 0.1f * Nf * pe) * (1.f / 0.9f);  // (-tau*N*pos + rw)/(1-tau)
        Ng = fmaxf(Ng, Nf * 0.13533528323661270f);        // N * e^{-1/t}
        float loss = logf((pe + Ng + 1e-8f) / pe);
#pragma unroll
        for (int off = 32; off > 0; off >>= 1) loss += __shfl_down(loss, off, 64);
        if (lane == 0) atomicAdd(out, loss / (float)B);
    }
}

extern "C" void kernel_launch(void* const* d_in, const int* in_sizes, int n_in,
                              void* d_out, int out_size, void* d_ws, size_t ws_size,
                              hipStream_t stream) {
    const float* L = (const float*)d_in[0];
    int B = 1;
    while ((long long)B * B < (long long)in_sizes[0]) B <<= 1;  // B = 4096
    const int S = B / 4;                                        // 1024 row stripes

    float* rowPE  = (float*)d_ws;               // 4*B
    float* rowPE2 = rowPE  + (size_t)4 * B;     // 4*B
    float* colPE  = rowPE2 + (size_t)4 * B;     // S*B
    float* colPE2 = colPE  + (size_t)S * B;     // S*B
    // ws bytes: (8*B + 2*S*B)*4 = 33.7 MB for B=4096

    hipMemsetAsync(d_out, 0, sizeof(float), stream);

    dim3 grid1(4, B / 16);                      // (4, 256) = 1024 blocks, 4 waves each
    pass1_kernel<<<grid1, THREADS, 0, stream>>>(L, rowPE, rowPE2, colPE, colPE2, B);
    pass2_kernel<<<B / 64, THREADS, 0, stream>>>(L, rowPE, rowPE2, colPE, colPE2,
                                                 (float*)d_out, B, S);
}

// Round 4
// 100.921 us; speedup vs baseline: 1.1030x; 1.1030x over previous
//
#include <hip/hip_runtime.h>
#include <math.h>

// ClipStyleContrastiveLoss on MI355X (gfx950).
// Math reduction (BETA=1 => imp==neg):
//   E = exp(L/t), exp(2L/t) = E^2
//   S1[i] = rowsum(E)[i] + colsum(E)[i] - 2*E[i,i]
//   S2[i] = rowsum(E^2)[i] + colsum(E^2)[i] - 2*E[i,i]^2
//   reweight = N*S2/S1 ; Ng = (reweight - tau*N*pos)/(1-tau), clamped at N*e^{-1/t}
//   loss = mean over B rows of log((pos+Ng+eps)/pos)
//
// R4: R3's atomic-free wave structure + intra-block LDS cross-wave col-combine
// (R3 lacked it: 4x the partial volume, and its 64-block pass2 was latency-bound).
// colP packed float2(E,E2), S=256 stripes -> 8.4 MB partials (was 33.5 MB).

#define THREADS    256
// 1/(TEMPERATURE*ln2) = 2/ln2 : exp(x/t) = exp2(x*EXP_SCALE)
#define EXP_SCALE  2.885390081777927f

__global__ __launch_bounds__(THREADS) void pass1_kernel(
    const float* __restrict__ L,
    float2* __restrict__ rowP,   // [4][B]  (E,E2) row sums per col-stripe
    float2* __restrict__ colP,   // [S][B]  (E,E2) col partials, S = B/16
    int B)
{
    __shared__ float ldsE [4][1024];   // 16 KB
    __shared__ float ldsE2[4][1024];   // 16 KB

    const int t       = threadIdx.x;
    const int lane    = t & 63;
    const int wave    = t >> 6;
    const int x       = blockIdx.x;            // col stripe (1024 cols)
    const int s       = blockIdx.y;            // row stripe (16 rows)
    const int row0    = s * 16 + wave * 4;     // wave's 4 rows
    const int colBase = x * 1024 + lane * 4;

    float cE[16], cE2[16], rs[4], rs2[4];
#pragma unroll
    for (int k = 0; k < 16; ++k) { cE[k] = 0.f; cE2[k] = 0.f; }

#pragma unroll
    for (int r = 0; r < 4; ++r) {
        const float* Lr = L + (size_t)(row0 + r) * B + colBase;
        float a = 0.f, b = 0.f;
#pragma unroll
        for (int j = 0; j < 4; ++j) {
            const float4 v = *reinterpret_cast<const float4*>(Lr + j * 256);
            float e0 = exp2f(v.x * EXP_SCALE);
            float e1 = exp2f(v.y * EXP_SCALE);
            float e2 = exp2f(v.z * EXP_SCALE);
            float e3 = exp2f(v.w * EXP_SCALE);
            float q0 = e0 * e0, q1 = e1 * e1, q2 = e2 * e2, q3 = e3 * e3;
            cE [j*4+0] += e0; cE [j*4+1] += e1; cE [j*4+2] += e2; cE [j*4+3] += e3;
            cE2[j*4+0] += q0; cE2[j*4+1] += q1; cE2[j*4+2] += q2; cE2[j*4+3] += q3;
            a += (e0 + e1) + (e2 + e3);
            b += (q0 + q1) + (q2 + q3);
        }
        rs[r] = a; rs2[r] = b;
    }

    // Deferred row reductions (out of the load loop — no per-row dep barrier).
#pragma unroll
    for (int r = 0; r < 4; ++r) {
        float a = rs[r], b = rs2[r];
#pragma unroll
        for (int off = 32; off > 0; off >>= 1) {
            a += __shfl_down(a, off, 64);
            b += __shfl_down(b, off, 64);
        }
        if (lane == 0) rowP[(size_t)x * B + row0 + r] = make_float2(a, b);
    }

    // Cross-wave col combine: each wave dumps its partials (float4 writes),
    // then all threads sum the 4 waves per column (stride-1 reads, conflict-free).
#pragma unroll
    for (int j = 0; j < 4; ++j) {
        *reinterpret_cast<float4*>(&ldsE [wave][lane * 4 + j * 256]) =
            make_float4(cE [j*4+0], cE [j*4+1], cE [j*4+2], cE [j*4+3]);
        *reinterpret_cast<float4*>(&ldsE2[wave][lane * 4 + j * 256]) =
            make_float4(cE2[j*4+0], cE2[j*4+1], cE2[j*4+2], cE2[j*4+3]);
    }
    __syncthreads();

#pragma unroll
    for (int m = 0; m < 4; ++m) {
        const int c = t + m * 256;
        float se  = (ldsE [0][c] + ldsE [1][c]) + (ldsE [2][c] + ldsE [3][c]);
        float se2 = (ldsE2[0][c] + ldsE2[1][c]) + (ldsE2[2][c] + ldsE2[3][c]);
        colP[(size_t)s * B + x * 1024 + c] = make_float2(se, se2);   // coalesced 8B
    }
}

// Merge S=256 stripe partials + row sums + diag -> loss; 256 blocks x 16 cols.
__global__ __launch_bounds__(THREADS) void pass2_kernel(
    const float* __restrict__ L,
    const float2* __restrict__ rowP,
    const float2* __restrict__ colP,
    float* __restrict__ out,
    int B, int S)
{
    const int t    = threadIdx.x;
    const int c    = t & 15;
    const int g    = t >> 4;
    const int base = blockIdx.x * 16;

    float se = 0.f, se2 = 0.f;
    for (int k = g; k < S; k += 16) {
        const float2 v = colP[(size_t)k * B + base + c];
        se += v.x; se2 += v.y;
    }
    __shared__ float2 part[16][17];
    part[g][c] = make_float2(se, se2);
    __syncthreads();

    if (t < 16) {
        float colE = 0.f, colE2 = 0.f;
#pragma unroll
        for (int gg = 0; gg < 16; ++gg) {
            colE  += part[gg][t].x;
            colE2 += part[gg][t].y;
        }
        const int i = base + t;
        float rowE = 0.f, rowE2 = 0.f;
#pragma unroll
        for (int x = 0; x < 4; ++x) {
            const float2 rv = rowP[(size_t)x * B + i];
            rowE += rv.x; rowE2 += rv.y;
        }
        const float Nf = (float)(2 * B - 2);
        float dg = L[(size_t)i * B + i];
        float pe = exp2f(dg * EXP_SCALE);
        float S1 = rowE  + colE  - 2.f * pe;
        float S2 = rowE2 + colE2 - 2.f * (pe * pe);
        float rw = Nf * (S2 / S1);                        // N * sum(neg^2)/sum(neg)
        float Ng = (rw - 0.1f * Nf * pe) * (1.f / 0.9f);  // (-tau*N*pos + rw)/(1-tau)
        Ng = fmaxf(Ng, Nf * 0.13533528323661270f);        // N * e^{-1/t}
        float loss = logf((pe + Ng + 1e-8f) / pe);
#pragma unroll
        for (int off = 8; off > 0; off >>= 1) loss += __shfl_down(loss, off, 16);
        if (t == 0) atomicAdd(out, loss / (float)B);
    }
}

extern "C" void kernel_launch(void* const* d_in, const int* in_sizes, int n_in,
                              void* d_out, int out_size, void* d_ws, size_t ws_size,
                              hipStream_t stream) {
    const float* L = (const float*)d_in[0];
    int B = 1;
    while ((long long)B * B < (long long)in_sizes[0]) B <<= 1;  // B = 4096
    const int S = B / 16;                                       // 256 row stripes

    float2* rowP = (float2*)d_ws;                   // 4*B float2 = 256 KB
    float2* colP = rowP + (size_t)4 * B;            // S*B float2 = 8.4 MB

    hipMemsetAsync(d_out, 0, sizeof(float), stream);

    dim3 grid1(4, B / 16);                          // (4, 256) = 1024 blocks
    pass1_kernel<<<grid1, THREADS, 0, stream>>>(L, rowP, colP, B);
    pass2_kernel<<<B / 16, THREADS, 0, stream>>>(L, rowP, colP, (float*)d_out, B, S);
}